// Round 2
// baseline (108.777 us; speedup 1.0000x reference)
//
#include <hip/hip_runtime.h>

#define NCLS 512
#define DIM 512
#define D4 (DIM / 4)      // float4 per row = 128
#define NSL 4             // D-slices per class
#define SL_D4 (D4 / NSL)  // float4 per slice = 32
#define EPS 1e-6f
#define MARGIN 1.0f

// Kernel A: label histogram + exclusive scan + zero total/out. One block.
__global__ __launch_bounds__(1024)
void k_prep(const int* __restrict__ lab, int N,
            int* __restrict__ cnts, int* __restrict__ offsets, int* __restrict__ cur,
            float* __restrict__ total, float* __restrict__ d_out)
{
    __shared__ int h[NCLS];
    const int t = threadIdx.x;
    if (t < NCLS) h[t] = 0;
    __syncthreads();

    const int4* lab4 = (const int4*)lab;
    const int nv = N >> 2;
    for (int j = t; j < nv; j += 1024) {
        int4 l = lab4[j];
        atomicAdd(&h[l.x], 1);
        atomicAdd(&h[l.y], 1);
        atomicAdd(&h[l.z], 1);
        atomicAdd(&h[l.w], 1);
    }
    __syncthreads();

    const int myc = (t < NCLS) ? h[t] : 0;

    // Hillis-Steele inclusive scan over h[0..511]; all 1024 threads hit barriers
    for (int o = 1; o < NCLS; o <<= 1) {
        int add = 0;
        if (t < NCLS && t >= o) add = h[t - o];
        __syncthreads();
        if (t < NCLS) h[t] += add;
        __syncthreads();
    }

    if (t < NCLS) {
        const int excl = h[t] - myc;
        cnts[t]    = myc;
        offsets[t] = excl;
        cur[t]     = excl;
        total[t]   = 0.f;
    }
    if (t == 0) d_out[0] = 0.f;
}

// Kernel B: scatter sample indices into class-sorted order.
__global__ __launch_bounds__(256)
void k_scatter(const int* __restrict__ lab, int* __restrict__ cur,
               int* __restrict__ sorted, int N)
{
    int i = blockIdx.x * blockDim.x + threadIdx.x;
    const int stride = gridDim.x * blockDim.x;
    for (; i < N; i += stride) {
        const int c = lab[i];
        const int p = atomicAdd(&cur[c], 1);
        sorted[p] = i;
    }
}

// Kernel C: per (class, D-slice) gather-sum with float4 loads.
// 8 rows per iteration (256 threads / 32 float4-per-slice).
__global__ __launch_bounds__(256)
void k_gather(const float4* __restrict__ x4, const int* __restrict__ sorted,
              const int* __restrict__ offsets, const int* __restrict__ cnts,
              float4* __restrict__ cls_sums4, float* __restrict__ total)
{
    const int b    = blockIdx.x;
    const int c    = b >> 2;
    const int sl   = b & 3;
    const int t    = threadIdx.x;
    const int d4   = t & (SL_D4 - 1);   // float4 index within slice
    const int rsub = t >> 5;            // 0..7
    const int off  = offsets[c];
    const int cnt  = cnts[c];
    const int col  = sl * SL_D4 + d4;   // float4 index within row

    float4 acc = make_float4(0.f, 0.f, 0.f, 0.f);
    int r = rsub;
    if (r < cnt) {
        int row = sorted[off + r];
        for (;;) {
            const int nr = r + 8;
            const int nrow = (nr < cnt) ? sorted[off + nr] : 0;  // prefetch index
            const float4 v = x4[(size_t)row * D4 + col];
            acc.x += v.x; acc.y += v.y; acc.z += v.z; acc.w += v.w;
            if (nr >= cnt) break;
            r = nr; row = nrow;
        }
    }

    __shared__ float4 red[256];
    red[t] = acc;
    __syncthreads();

    if (t < SL_D4) {
        float4 s = red[t];
        #pragma unroll
        for (int k = 1; k < 8; ++k) {
            const float4 o = red[t + SL_D4 * k];
            s.x += o.x; s.y += o.y; s.z += o.z; s.w += o.w;
        }
        cls_sums4[(size_t)c * D4 + col] = s;
        float* tp = total + col * 4;
        atomicAdd(tp + 0, s.x);
        atomicAdd(tp + 1, s.y);
        atomicAdd(tp + 2, s.z);
        atomicAdd(tp + 3, s.w);
    }
}

// Kernel D: per class, d_c = ||s/c - (total-s)/(N-c) + eps||; accumulate loss.
__global__ __launch_bounds__(256)
void k_finalize(const float* __restrict__ cls_sums, const int* __restrict__ cnts,
                const float* __restrict__ total, float* __restrict__ d_out, int N)
{
    const int c   = blockIdx.x;
    const int tid = threadIdx.x;
    const int cnt = cnts[c];

    const float2 s = ((const float2*)cls_sums)[c * (DIM / 2) + tid];
    const float2 t = ((const float2*)total)[tid];

    float ss = 0.f;
    if (cnt > 0) {
        const float inv_c  = 1.f / (float)cnt;
        const float inv_nc = 1.f / (float)(N - cnt);
        const float d0 = s.x * inv_c - (t.x - s.x) * inv_nc + EPS;
        const float d1 = s.y * inv_c - (t.y - s.y) * inv_nc + EPS;
        ss = d0 * d0 + d1 * d1;
    }

    #pragma unroll
    for (int o = 1; o < 64; o <<= 1) ss += __shfl_xor(ss, o, 64);

    __shared__ float s_red[4];
    if ((tid & 63) == 0) s_red[tid >> 6] = ss;
    __syncthreads();

    if (tid == 0) {
        const float tot = (s_red[0] + s_red[1]) + (s_red[2] + s_red[3]);
        const float d = sqrtf(tot);
        const float w = fmaxf(MARGIN - d, 0.f);
        if (cnt > 0) atomicAdd(d_out, (float)cnt * w * w / (float)N);
    }
}

extern "C" void kernel_launch(void* const* d_in, const int* in_sizes, int n_in,
                              void* d_out, int out_size, void* d_ws, size_t ws_size,
                              hipStream_t stream)
{
    const float* x   = (const float*)d_in[0];
    const int*   lab = (const int*)d_in[1];
    float*       out = (float*)d_out;

    const int N = in_sizes[1];  // 65536 samples

    float* cls_sums = (float*)d_ws;                    // NCLS*DIM f32 = 1 MiB
    float* total    = cls_sums + (size_t)NCLS * DIM;   // DIM f32
    int*   cnts     = (int*)(total + DIM);             // NCLS
    int*   offsets  = cnts + NCLS;                     // NCLS
    int*   cur      = offsets + NCLS;                  // NCLS
    int*   sorted   = cur + NCLS;                      // N

    k_prep<<<1, 1024, 0, stream>>>(lab, N, cnts, offsets, cur, total, out);
    k_scatter<<<64, 256, 0, stream>>>(lab, cur, sorted, N);
    k_gather<<<NCLS * NSL, 256, 0, stream>>>((const float4*)x, sorted, offsets, cnts,
                                             (float4*)cls_sums, total);
    k_finalize<<<NCLS, 256, 0, stream>>>(cls_sums, cnts, total, out, N);
}